// Round 1
// baseline (3360.479 us; speedup 1.0000x reference)
//
#include <hip/hip_runtime.h>

constexpr int NN = 50000;   // nodes
constexpr int NE = 800000;  // edges
constexpr int NG = 64;      // graphs
constexpr int DI = 64;      // in dim
constexpr int DH = 128;     // hidden dim
constexpr int DO = 3;       // out dim

// ---------------- degree / norm ----------------
__global__ void k_init_deg(float* deg) {
    int i = blockIdx.x * blockDim.x + threadIdx.x;
    if (i < NN) deg[i] = 1.0f;  // self-loop
}

__global__ void k_edge_deg(const int* __restrict__ dst, float* __restrict__ deg) {
    int i = blockIdx.x * blockDim.x + threadIdx.x;
    if (i < NE) atomicAdd(&deg[dst[i]], 1.0f);
}

__global__ void k_dinv(float* deg) {
    int i = blockIdx.x * blockDim.x + threadIdx.x;
    if (i < NN) deg[i] = rsqrtf(fmaxf(deg[i], 1.0f));
}

// ---------------- GEMM: C[n,DH] = A[n,DIN] @ W[DIN,DH] ----------------
template <int DIN>
__global__ __launch_bounds__(256) void k_gemm(const float* __restrict__ A,
                                              const float* __restrict__ W,
                                              float* __restrict__ C, int n) {
    __shared__ float sW[DIN * DH];
    __shared__ float sA[16 * DIN];
    const int t = threadIdx.x;
    for (int i = t; i < DIN * DH; i += 256) sW[i] = W[i];
    const int row0 = blockIdx.x * 16;
    for (int i = t; i < 16 * DIN; i += 256) {
        int r = i / DIN, k = i - r * DIN;
        int gr = row0 + r;
        sA[i] = (gr < n) ? A[(size_t)gr * DIN + k] : 0.0f;
    }
    __syncthreads();
    const int col = t & 127;
    const int rbase = t >> 7;  // 0 or 1
    for (int r = rbase; r < 16; r += 2) {
        float acc = 0.0f;
#pragma unroll
        for (int k = 0; k < DIN; ++k)
            acc = fmaf(sA[r * DIN + k], sW[k * DH + col], acc);
        int gr = row0 + r;
        if (gr < n) C[(size_t)gr * DH + col] = acc;
    }
}

// ---------------- self-loop init: out[i,:] = dinv[i]^2 * h[i,:] ----------------
__global__ void k_selfloop(const float* __restrict__ h, const float* __restrict__ dinv,
                           float* __restrict__ out) {
    int i = blockIdx.x * blockDim.x + threadIdx.x;  // over NN*32 float4 chunks
    if (i >= NN * (DH / 4)) return;
    int node = i >> 5;
    float d = dinv[node];
    float w = d * d;
    float4 hv = reinterpret_cast<const float4*>(h)[i];
    float4 o;
    o.x = w * hv.x; o.y = w * hv.y; o.z = w * hv.z; o.w = w * hv.w;
    reinterpret_cast<float4*>(out)[i] = o;
}

// ---------------- edge scatter: out[dst,:] += dinv[s]*dinv[d] * h[src,:] ----------------
__global__ void k_edge_agg(const int* __restrict__ src, const int* __restrict__ dst,
                           const float* __restrict__ dinv, const float* __restrict__ h,
                           float* __restrict__ out) {
    long long tid = (long long)blockIdx.x * blockDim.x + threadIdx.x;
    long long e = tid >> 5;  // 32 threads per edge
    if (e >= NE) return;
    int lane = (int)(tid & 31);
    int s = src[e], d = dst[e];
    float w = dinv[s] * dinv[d];
    float4 hv = *reinterpret_cast<const float4*>(h + (size_t)s * DH + lane * 4);
    float* o = out + (size_t)d * DH + lane * 4;
    atomicAdd(o + 0, w * hv.x);
    atomicAdd(o + 1, w * hv.y);
    atomicAdd(o + 2, w * hv.z);
    atomicAdd(o + 3, w * hv.w);
}

// ---------------- bias + relu in place ----------------
__global__ void k_bias_relu(float* __restrict__ h, const float* __restrict__ b) {
    int i = blockIdx.x * blockDim.x + threadIdx.x;  // over NN*32 float4 chunks
    if (i >= NN * (DH / 4)) return;
    int cb = (i & 31) * 4;
    float4 v = reinterpret_cast<const float4*>(h)[i];
    float4 bb = *reinterpret_cast<const float4*>(b + cb);
    v.x = fmaxf(v.x + bb.x, 0.0f);
    v.y = fmaxf(v.y + bb.y, 0.0f);
    v.z = fmaxf(v.z + bb.z, 0.0f);
    v.w = fmaxf(v.w + bb.w, 0.0f);
    reinterpret_cast<float4*>(h)[i] = v;
}

// ---------------- pooling ----------------
__global__ void k_pool_zero(float* __restrict__ pooled, float* __restrict__ counts) {
    int i = blockIdx.x * blockDim.x + threadIdx.x;
    if (i < NG * DH) pooled[i] = 0.0f;
    if (i < NG) counts[i] = 0.0f;
}

__global__ void k_pool(const float* __restrict__ h, const int* __restrict__ batch,
                       float* __restrict__ pooled, float* __restrict__ counts) {
    long long tid = (long long)blockIdx.x * blockDim.x + threadIdx.x;
    long long node = tid >> 5;
    if (node >= NN) return;
    int lane = (int)(tid & 31);
    int g = batch[node];
    float4 hv = *reinterpret_cast<const float4*>(h + (size_t)node * DH + lane * 4);
    float* p = pooled + (size_t)g * DH + lane * 4;
    atomicAdd(p + 0, hv.x);
    atomicAdd(p + 1, hv.y);
    atomicAdd(p + 2, hv.z);
    atomicAdd(p + 3, hv.w);
    if (lane == 0) atomicAdd(&counts[g], 1.0f);
}

// ---------------- head: out[g,o] = (pooled[g,:]/cnt) @ Wf[:,o] + bf[o] ----------------
__global__ void k_head(const float* __restrict__ pooled, const float* __restrict__ counts,
                       const float* __restrict__ Wf, const float* __restrict__ bf,
                       float* __restrict__ out) {
    int t = blockIdx.x * blockDim.x + threadIdx.x;
    if (t >= NG * DO) return;
    int g = t / DO, o = t - g * DO;
    float c = fmaxf(counts[g], 1.0f);
    float acc = 0.0f;
    for (int k = 0; k < DH; ++k)
        acc += pooled[(size_t)g * DH + k] * Wf[k * DO + o];
    out[t] = acc / c + bf[o];
}

extern "C" void kernel_launch(void* const* d_in, const int* in_sizes, int n_in,
                              void* d_out, int out_size, void* d_ws, size_t ws_size,
                              hipStream_t stream) {
    const float* x  = (const float*)d_in[0];
    const int* ei   = (const int*)d_in[1];   // [2, NE] row-major
    const int* batch= (const int*)d_in[2];
    const float* W1 = (const float*)d_in[3];
    const float* b1 = (const float*)d_in[4];
    const float* W2 = (const float*)d_in[5];
    const float* b2 = (const float*)d_in[6];
    const float* Wf = (const float*)d_in[7];
    const float* bf = (const float*)d_in[8];
    float* out = (float*)d_out;

    const int* src = ei;
    const int* dst = ei + NE;

    float* ws = (float*)d_ws;
    float* dinv   = ws;                         // NN floats (padded to 50048)
    float* bufA   = ws + 50048;                 // NN*DH
    float* bufB   = bufA + (size_t)NN * DH;     // NN*DH
    float* pooled = bufB + (size_t)NN * DH;     // NG*DH
    float* counts = pooled + NG * DH;           // NG

    const int B = 256;
    // degree / dinv
    k_init_deg<<<(NN + B - 1) / B, B, 0, stream>>>(dinv);
    k_edge_deg<<<(NE + B - 1) / B, B, 0, stream>>>(dst, dinv);
    k_dinv<<<(NN + B - 1) / B, B, 0, stream>>>(dinv);

    const int elem4 = NN * (DH / 4);
    const long long eth = (long long)NE * 32;

    // ---- layer 1 ----
    k_gemm<DI><<<(NN + 15) / 16, B, 0, stream>>>(x, W1, bufA, NN);
    k_selfloop<<<(elem4 + B - 1) / B, B, 0, stream>>>(bufA, dinv, bufB);
    k_edge_agg<<<(int)((eth + B - 1) / B), B, 0, stream>>>(src, dst, dinv, bufA, bufB);
    k_bias_relu<<<(elem4 + B - 1) / B, B, 0, stream>>>(bufB, b1);

    // ---- layer 2 ----
    k_gemm<DH><<<(NN + 15) / 16, B, 0, stream>>>(bufB, W2, bufA, NN);
    k_selfloop<<<(elem4 + B - 1) / B, B, 0, stream>>>(bufA, dinv, bufB);
    k_edge_agg<<<(int)((eth + B - 1) / B), B, 0, stream>>>(src, dst, dinv, bufA, bufB);
    k_bias_relu<<<(elem4 + B - 1) / B, B, 0, stream>>>(bufB, b2);

    // ---- pool + head ----
    k_pool_zero<<<(NG * DH + B - 1) / B, B, 0, stream>>>(pooled, counts);
    k_pool<<<(int)(((long long)NN * 32 + B - 1) / B), B, 0, stream>>>(bufB, batch, pooled, counts);
    k_head<<<1, 256, 0, stream>>>(pooled, counts, Wf, bf, out);
}

// Round 2
// 575.088 us; speedup vs baseline: 5.8434x; 5.8434x over previous
//
#include <hip/hip_runtime.h>

constexpr int NN = 50000;   // nodes
constexpr int NE = 800000;  // edges
constexpr int NG = 64;      // graphs
constexpr int DI = 64;      // in dim
constexpr int DH = 128;     // hidden dim
constexpr int DO = 3;       // out dim

constexpr int SCAN_B = 256;
constexpr int NB_SCAN = (NN + SCAN_B - 1) / SCAN_B;  // 196

// ---------------- CSR build ----------------
__global__ void k_zero_cnt(int* cnt) {
    int i = blockIdx.x * blockDim.x + threadIdx.x;
    if (i < NN) cnt[i] = 0;
}

__global__ void k_hist(const int* __restrict__ dst, int* __restrict__ cnt) {
    int e = blockIdx.x * blockDim.x + threadIdx.x;
    if (e < NE) atomicAdd(&cnt[dst[e]], 1);
}

__global__ void k_scan1(const int* __restrict__ cnt, int* __restrict__ rowptr,
                        int* __restrict__ partial) {
    __shared__ int sm[SCAN_B];
    int i = blockIdx.x * SCAN_B + threadIdx.x;
    int v = (i < NN) ? cnt[i] : 0;
    sm[threadIdx.x] = v;
    __syncthreads();
    for (int off = 1; off < SCAN_B; off <<= 1) {
        int add = (threadIdx.x >= off) ? sm[threadIdx.x - off] : 0;
        __syncthreads();
        sm[threadIdx.x] += add;
        __syncthreads();
    }
    if (i < NN) rowptr[i] = sm[threadIdx.x] - v;  // block-local exclusive
    if (threadIdx.x == SCAN_B - 1) partial[blockIdx.x] = sm[SCAN_B - 1];
}

__global__ void k_scan2(int* partial) {  // single block, NB_SCAN <= 256
    __shared__ int sm[SCAN_B];
    int v = (threadIdx.x < NB_SCAN) ? partial[threadIdx.x] : 0;
    sm[threadIdx.x] = v;
    __syncthreads();
    for (int off = 1; off < SCAN_B; off <<= 1) {
        int add = (threadIdx.x >= off) ? sm[threadIdx.x - off] : 0;
        __syncthreads();
        sm[threadIdx.x] += add;
        __syncthreads();
    }
    if (threadIdx.x < NB_SCAN) partial[threadIdx.x] = sm[threadIdx.x] - v;  // exclusive
}

__global__ void k_scan3(int* __restrict__ rowptr, const int* __restrict__ partial,
                        int* __restrict__ cursor) {
    int i = blockIdx.x * blockDim.x + threadIdx.x;
    if (i < NN) {
        int r = rowptr[i] + partial[i >> 8];
        rowptr[i] = r;
        cursor[i] = r;
    }
    if (i == NN) rowptr[NN] = NE;
}

__global__ void k_dinv(const int* __restrict__ cnt, float* __restrict__ dinv) {
    int i = blockIdx.x * blockDim.x + threadIdx.x;
    if (i < NN) dinv[i] = rsqrtf((float)(cnt[i] + 1));  // +1 self-loop, always >=1
}

__global__ void k_fill(const int* __restrict__ src, const int* __restrict__ dst,
                       int* __restrict__ cursor, int* __restrict__ csr_src) {
    int e = blockIdx.x * blockDim.x + threadIdx.x;
    if (e < NE) {
        int d = dst[e];
        int slot = atomicAdd(&cursor[d], 1);
        csr_src[slot] = src[e];
    }
}

// ---------------- gather aggregation: out[n] = dinv[n]^2*h[n] + sum_in dinv[n]dinv[s]h[s] ----------------
template <int D, bool BIAS_RELU>
__global__ __launch_bounds__(256) void k_agg(const float* __restrict__ h,
                                             const int* __restrict__ csr_src,
                                             const int* __restrict__ rowptr,
                                             const float* __restrict__ dinv,
                                             const float* __restrict__ bias,
                                             float* __restrict__ out) {
    constexpr int V = D / 64;  // floats per lane
    const int wave = threadIdx.x >> 6;
    const int lane = threadIdx.x & 63;
    const int node = blockIdx.x * 4 + wave;
    if (node >= NN) return;
    const float dn = dinv[node];
    float acc[V];
    {
        const float* hp = h + (size_t)node * D + lane * V;
#pragma unroll
        for (int v = 0; v < V; ++v) acc[v] = (dn * dn) * hp[v];
    }
    const int beg = rowptr[node], end = rowptr[node + 1];
    for (int j = beg; j < end; ++j) {
        const int s = csr_src[j];
        const float w = dn * dinv[s];
        const float* hp = h + (size_t)s * D + lane * V;
#pragma unroll
        for (int v = 0; v < V; ++v) acc[v] = fmaf(w, hp[v], acc[v]);
    }
    float* op = out + (size_t)node * D + lane * V;
#pragma unroll
    for (int v = 0; v < V; ++v) {
        float r = acc[v];
        if (BIAS_RELU) r = fmaxf(r + bias[lane * V + v], 0.0f);
        op[v] = r;
    }
}

// ---------------- GEMM: C[NN,DH] = A[NN,DIN] @ W[DIN,DH] (+bias, relu) ----------------
template <int DIN, bool BIAS_RELU>
__global__ __launch_bounds__(256) void k_gemm(const float* __restrict__ A,
                                              const float* __restrict__ W,
                                              const float* __restrict__ bias,
                                              float* __restrict__ C) {
    __shared__ float sW[DIN * DH];
    __shared__ float sA[16 * DIN];
    const int t = threadIdx.x;
    for (int i = t; i < DIN * DH; i += 256) sW[i] = W[i];
    const int row0 = blockIdx.x * 16;
    for (int i = t; i < 16 * DIN; i += 256) {
        int r = i / DIN, k = i - r * DIN;
        int gr = row0 + r;
        sA[i] = (gr < NN) ? A[(size_t)gr * DIN + k] : 0.0f;
    }
    __syncthreads();
    const int col = t & 127;
    const int rb = t >> 7;  // 0 or 1
    float acc[8] = {0.f, 0.f, 0.f, 0.f, 0.f, 0.f, 0.f, 0.f};
#pragma unroll 8
    for (int k = 0; k < DIN; ++k) {
        float w = sW[k * DH + col];
#pragma unroll
        for (int j = 0; j < 8; ++j)
            acc[j] = fmaf(sA[(rb + 2 * j) * DIN + k], w, acc[j]);
    }
    float b = BIAS_RELU ? bias[col] : 0.0f;
#pragma unroll
    for (int j = 0; j < 8; ++j) {
        int gr = row0 + rb + 2 * j;
        if (gr < NN) {
            float r = acc[j];
            if (BIAS_RELU) r = fmaxf(r + b, 0.0f);
            C[(size_t)gr * DH + col] = r;
        }
    }
}

// ---------------- pooling (batch sorted -> segment boundaries via bsearch) ----------------
__global__ void k_gstart(const int* __restrict__ batch, int* __restrict__ gstart) {
    int g = threadIdx.x;
    if (g > NG) return;
    int lo = 0, hi = NN;
    while (lo < hi) {
        int mid = (lo + hi) >> 1;
        if (batch[mid] < g) lo = mid + 1; else hi = mid;
    }
    gstart[g] = lo;
}

__global__ void k_pool(const float* __restrict__ h, const int* __restrict__ gstart,
                       float* __restrict__ pooled) {
    int g = blockIdx.x;   // 64
    int c = threadIdx.x;  // 128
    int beg = gstart[g], end = gstart[g + 1];
    float acc = 0.0f;
    for (int n = beg; n < end; ++n) acc += h[(size_t)n * DH + c];
    float cnt = fmaxf((float)(end - beg), 1.0f);
    pooled[g * DH + c] = acc / cnt;
}

__global__ void k_head(const float* __restrict__ pooled, const float* __restrict__ Wf,
                       const float* __restrict__ bf, float* __restrict__ out) {
    int t = threadIdx.x;
    if (t >= NG * DO) return;
    int g = t / DO, o = t - g * DO;
    float acc = 0.0f;
    for (int k = 0; k < DH; ++k) acc += pooled[g * DH + k] * Wf[k * DO + o];
    out[t] = acc + bf[o];
}

extern "C" void kernel_launch(void* const* d_in, const int* in_sizes, int n_in,
                              void* d_out, int out_size, void* d_ws, size_t ws_size,
                              hipStream_t stream) {
    const float* x   = (const float*)d_in[0];
    const int* ei    = (const int*)d_in[1];  // [2, NE] row-major
    const int* batch = (const int*)d_in[2];
    const float* W1  = (const float*)d_in[3];
    const float* b1  = (const float*)d_in[4];
    const float* W2  = (const float*)d_in[5];
    const float* b2  = (const float*)d_in[6];
    const float* Wf  = (const float*)d_in[7];
    const float* bf  = (const float*)d_in[8];
    float* out = (float*)d_out;

    const int* src = ei;
    const int* dst = ei + NE;

    // workspace layout (all 4B elems; buf offsets even -> 8B aligned)
    int* cnt      = (int*)d_ws;              // 50048
    int* rowptr   = cnt + 50048;             // 50056 (NN+1 used)
    int* cursor   = rowptr + 50056;          // 50048
    int* partial  = cursor + 50048;          // 256
    int* gstart   = partial + 256;           // 72
    int* csr_src  = gstart + 72;             // 800000
    float* dinv   = (float*)(csr_src + 800000);  // 50048
    float* buf1   = dinv + 50048;            // 6,400,000
    float* buf2   = buf1 + 6400000;          // 6,400,000
    float* pooled = buf2 + 6400000;          // 8192

    const int B = 256;
    // CSR build + norms
    k_zero_cnt<<<(NN + B - 1) / B, B, 0, stream>>>(cnt);
    k_hist<<<(NE + B - 1) / B, B, 0, stream>>>(dst, cnt);
    k_scan1<<<NB_SCAN, SCAN_B, 0, stream>>>(cnt, rowptr, partial);
    k_scan2<<<1, SCAN_B, 0, stream>>>(partial);
    k_scan3<<<(NN + B) / B, B, 0, stream>>>(rowptr, partial, cursor);
    k_dinv<<<(NN + B - 1) / B, B, 0, stream>>>(cnt, dinv);
    k_fill<<<(NE + B - 1) / B, B, 0, stream>>>(src, dst, cursor, csr_src);

    const int aggGrid = (NN + 3) / 4;
    const int gemmGrid = (NN + 15) / 16;

    // layer 1: agg first (D=64, linearity), then GEMM + bias + relu
    k_agg<DI, false><<<aggGrid, 256, 0, stream>>>(x, csr_src, rowptr, dinv, nullptr, buf1);
    k_gemm<DI, true><<<gemmGrid, 256, 0, stream>>>(buf1, W1, b1, buf2);  // h1

    // layer 2: GEMM first, then agg + bias + relu
    k_gemm<DH, false><<<gemmGrid, 256, 0, stream>>>(buf2, W2, nullptr, buf1);  // t = h1@W2
    k_agg<DH, true><<<aggGrid, 256, 0, stream>>>(buf1, csr_src, rowptr, dinv, b2, buf2);  // h2

    // pool + head
    k_gstart<<<1, 128, 0, stream>>>(batch, gstart);
    k_pool<<<NG, DH, 0, stream>>>(buf2, gstart, pooled);
    k_head<<<1, 256, 0, stream>>>(pooled, Wf, bf, out);
}

// Round 3
// 392.090 us; speedup vs baseline: 8.5707x; 1.4667x over previous
//
#include <hip/hip_runtime.h>

constexpr int NN = 50000;   // nodes
constexpr int NE = 800000;  // edges
constexpr int NG = 64;      // graphs
constexpr int DI = 64;      // in dim
constexpr int DH = 128;     // hidden dim
constexpr int DO = 3;       // out dim

constexpr int SCAN_B = 256;
constexpr int NB_SCAN = (NN + SCAN_B - 1) / SCAN_B;  // 196

// ---------------- CSR build ----------------
__global__ void k_zero_cnt(int* cnt) {
    int i = blockIdx.x * blockDim.x + threadIdx.x;
    if (i < NN) cnt[i] = 0;
}

__global__ void k_hist(const int* __restrict__ dst, int* __restrict__ cnt) {
    int e = blockIdx.x * blockDim.x + threadIdx.x;
    if (e < NE) atomicAdd(&cnt[dst[e]], 1);
}

__global__ void k_scan1(const int* __restrict__ cnt, int* __restrict__ rowptr,
                        int* __restrict__ partial) {
    __shared__ int sm[SCAN_B];
    int i = blockIdx.x * SCAN_B + threadIdx.x;
    int v = (i < NN) ? cnt[i] : 0;
    sm[threadIdx.x] = v;
    __syncthreads();
    for (int off = 1; off < SCAN_B; off <<= 1) {
        int add = (threadIdx.x >= off) ? sm[threadIdx.x - off] : 0;
        __syncthreads();
        sm[threadIdx.x] += add;
        __syncthreads();
    }
    if (i < NN) rowptr[i] = sm[threadIdx.x] - v;  // block-local exclusive
    if (threadIdx.x == SCAN_B - 1) partial[blockIdx.x] = sm[SCAN_B - 1];
}

__global__ void k_scan2(int* partial) {  // single block, NB_SCAN <= 256
    __shared__ int sm[SCAN_B];
    int v = (threadIdx.x < NB_SCAN) ? partial[threadIdx.x] : 0;
    sm[threadIdx.x] = v;
    __syncthreads();
    for (int off = 1; off < SCAN_B; off <<= 1) {
        int add = (threadIdx.x >= off) ? sm[threadIdx.x - off] : 0;
        __syncthreads();
        sm[threadIdx.x] += add;
        __syncthreads();
    }
    if (threadIdx.x < NB_SCAN) partial[threadIdx.x] = sm[threadIdx.x] - v;  // exclusive
}

__global__ void k_scan3(int* __restrict__ rowptr, const int* __restrict__ partial,
                        int* __restrict__ cursor) {
    int i = blockIdx.x * blockDim.x + threadIdx.x;
    if (i < NN) {
        int r = rowptr[i] + partial[i >> 8];
        rowptr[i] = r;
        cursor[i] = r;
    }
    if (i == NN) rowptr[NN] = NE;
}

__global__ void k_dinv(const int* __restrict__ cnt, float* __restrict__ dinv) {
    int i = blockIdx.x * blockDim.x + threadIdx.x;
    if (i < NN) dinv[i] = rsqrtf((float)(cnt[i] + 1));  // +1 self-loop, always >=1
}

__global__ void k_fill(const int* __restrict__ src, const int* __restrict__ dst,
                       int* __restrict__ cursor, int* __restrict__ csr_src) {
    int e = blockIdx.x * blockDim.x + threadIdx.x;
    if (e < NE) {
        int d = dst[e];
        int slot = atomicAdd(&cursor[d], 1);
        csr_src[slot] = src[e];
    }
}

// ---------------- gather aggregation: out[n] = dinv[n]^2*h[n] + sum_in dinv[n]dinv[s]h[s] ----------------
template <int D, bool BIAS_RELU>
__global__ __launch_bounds__(256) void k_agg(const float* __restrict__ h,
                                             const int* __restrict__ csr_src,
                                             const int* __restrict__ rowptr,
                                             const float* __restrict__ dinv,
                                             const float* __restrict__ bias,
                                             float* __restrict__ out) {
    constexpr int V = D / 64;  // floats per lane
    const int wave = threadIdx.x >> 6;
    const int lane = threadIdx.x & 63;
    const int node = blockIdx.x * 4 + wave;
    if (node >= NN) return;
    const float dn = dinv[node];
    float acc[V];
    {
        const float* hp = h + (size_t)node * D + lane * V;
#pragma unroll
        for (int v = 0; v < V; ++v) acc[v] = (dn * dn) * hp[v];
    }
    const int beg = rowptr[node], end = rowptr[node + 1];
    for (int j = beg; j < end; ++j) {
        const int s = csr_src[j];
        const float w = dn * dinv[s];
        const float* hp = h + (size_t)s * D + lane * V;
#pragma unroll
        for (int v = 0; v < V; ++v) acc[v] = fmaf(w, hp[v], acc[v]);
    }
    float* op = out + (size_t)node * D + lane * V;
#pragma unroll
    for (int v = 0; v < V; ++v) {
        float r = acc[v];
        if (BIAS_RELU) r = fmaxf(r + bias[lane * V + v], 0.0f);
        op[v] = r;
    }
}

// ---------------- GEMM: C[NN,DH] = A[NN,DIN] @ W[DIN,DH] (+bias, relu) ----------------
template <int DIN, bool BIAS_RELU>
__global__ __launch_bounds__(256) void k_gemm(const float* __restrict__ A,
                                              const float* __restrict__ W,
                                              const float* __restrict__ bias,
                                              float* __restrict__ C) {
    __shared__ float sW[DIN * DH];
    __shared__ float sA[16 * DIN];
    const int t = threadIdx.x;
    for (int i = t; i < DIN * DH; i += 256) sW[i] = W[i];
    const int row0 = blockIdx.x * 16;
    for (int i = t; i < 16 * DIN; i += 256) {
        int r = i / DIN, k = i - r * DIN;
        int gr = row0 + r;
        sA[i] = (gr < NN) ? A[(size_t)gr * DIN + k] : 0.0f;
    }
    __syncthreads();
    const int col = t & 127;
    const int rb = t >> 7;  // 0 or 1
    float acc[8] = {0.f, 0.f, 0.f, 0.f, 0.f, 0.f, 0.f, 0.f};
#pragma unroll 8
    for (int k = 0; k < DIN; ++k) {
        float w = sW[k * DH + col];
#pragma unroll
        for (int j = 0; j < 8; ++j)
            acc[j] = fmaf(sA[(rb + 2 * j) * DIN + k], w, acc[j]);
    }
    float b = BIAS_RELU ? bias[col] : 0.0f;
#pragma unroll
    for (int j = 0; j < 8; ++j) {
        int gr = row0 + rb + 2 * j;
        if (gr < NN) {
            float r = acc[j];
            if (BIAS_RELU) r = fmaxf(r + b, 0.0f);
            C[(size_t)gr * DH + col] = r;
        }
    }
}

// ---------------- pooling ----------------
// gstart bsearch (block 0) + zero pooled (all blocks). grid: 32 x 256
__global__ void k_gstart_zero(const int* __restrict__ batch, int* __restrict__ gstart,
                              float* __restrict__ pooled) {
    int i = blockIdx.x * blockDim.x + threadIdx.x;
    if (i < NG * DH) pooled[i] = 0.0f;
    if (blockIdx.x == 0 && threadIdx.x <= NG) {
        int g = threadIdx.x;
        int lo = 0, hi = NN;
        while (lo < hi) {
            int mid = (lo + hi) >> 1;
            if (batch[mid] < g) lo = mid + 1; else hi = mid;
        }
        gstart[g] = lo;
    }
}

// chunked segmented sum: each block owns POOL_CHUNK contiguous nodes (batch sorted),
// accumulates per-graph in registers, flushes one atomicAdd per graph transition.
constexpr int POOL_CHUNK = 64;
__global__ __launch_bounds__(256) void k_pool2(const float* __restrict__ h,
                                               const int* __restrict__ batch,
                                               float* __restrict__ pooled) {
    const int c = threadIdx.x & 127;    // channel
    const int half = threadIdx.x >> 7;  // 0/1: interleaved nodes
    const int n0 = blockIdx.x * POOL_CHUNK;
    const int nEnd = min(n0 + POOL_CHUNK, NN);
    float acc = 0.0f;
    int gcur = -1;
    for (int n = n0 + half; n < nEnd; n += 2) {
        int g = batch[n];
        if (g != gcur) {
            if (gcur >= 0) atomicAdd(&pooled[gcur * DH + c], acc);
            acc = 0.0f;
            gcur = g;
        }
        acc += h[(size_t)n * DH + c];
    }
    if (gcur >= 0) atomicAdd(&pooled[gcur * DH + c], acc);
}

// head: out[g,o] = (sum_k pooled[g,k]*Wf[k,o]) / cnt[g] + bf[o]
__global__ void k_head(const float* __restrict__ pooled, const int* __restrict__ gstart,
                       const float* __restrict__ Wf, const float* __restrict__ bf,
                       float* __restrict__ out) {
    int t = threadIdx.x;
    if (t >= NG * DO) return;
    int g = t / DO, o = t - g * DO;
    float acc = 0.0f;
    for (int k = 0; k < DH; ++k) acc += pooled[g * DH + k] * Wf[k * DO + o];
    float cnt = fmaxf((float)(gstart[g + 1] - gstart[g]), 1.0f);
    out[t] = acc / cnt + bf[o];
}

extern "C" void kernel_launch(void* const* d_in, const int* in_sizes, int n_in,
                              void* d_out, int out_size, void* d_ws, size_t ws_size,
                              hipStream_t stream) {
    const float* x   = (const float*)d_in[0];
    const int* ei    = (const int*)d_in[1];  // [2, NE] row-major
    const int* batch = (const int*)d_in[2];
    const float* W1  = (const float*)d_in[3];
    const float* b1  = (const float*)d_in[4];
    const float* W2  = (const float*)d_in[5];
    const float* b2  = (const float*)d_in[6];
    const float* Wf  = (const float*)d_in[7];
    const float* bf  = (const float*)d_in[8];
    float* out = (float*)d_out;

    const int* src = ei;
    const int* dst = ei + NE;

    // workspace layout (all 4B elems)
    int* cnt      = (int*)d_ws;              // 50048
    int* rowptr   = cnt + 50048;             // 50056 (NN+1 used)
    int* cursor   = rowptr + 50056;          // 50048
    int* partial  = cursor + 50048;          // 256
    int* gstart   = partial + 256;           // 72
    int* csr_src  = gstart + 72;             // 800000
    float* dinv   = (float*)(csr_src + 800000);  // 50048
    float* buf1   = dinv + 50048;            // 6,400,000
    float* buf2   = buf1 + 6400000;          // 6,400,000
    float* pooled = buf2 + 6400000;          // 8192

    const int B = 256;
    // CSR build + norms
    k_zero_cnt<<<(NN + B - 1) / B, B, 0, stream>>>(cnt);
    k_hist<<<(NE + B - 1) / B, B, 0, stream>>>(dst, cnt);
    k_scan1<<<NB_SCAN, SCAN_B, 0, stream>>>(cnt, rowptr, partial);
    k_scan2<<<1, SCAN_B, 0, stream>>>(partial);
    k_scan3<<<(NN + B) / B, B, 0, stream>>>(rowptr, partial, cursor);
    k_dinv<<<(NN + B - 1) / B, B, 0, stream>>>(cnt, dinv);
    k_fill<<<(NE + B - 1) / B, B, 0, stream>>>(src, dst, cursor, csr_src);

    const int aggGrid = (NN + 3) / 4;
    const int gemmGrid = (NN + 15) / 16;

    // layer 1: agg first (D=64, linearity), then GEMM + bias + relu
    k_agg<DI, false><<<aggGrid, 256, 0, stream>>>(x, csr_src, rowptr, dinv, nullptr, buf1);
    k_gemm<DI, true><<<gemmGrid, 256, 0, stream>>>(buf1, W1, b1, buf2);  // h1

    // layer 2: GEMM first, then agg + bias + relu
    k_gemm<DH, false><<<gemmGrid, 256, 0, stream>>>(buf2, W2, nullptr, buf1);  // t = h1@W2
    k_agg<DH, true><<<aggGrid, 256, 0, stream>>>(buf1, csr_src, rowptr, dinv, b2, buf2);  // h2

    // pool + head
    k_gstart_zero<<<32, 256, 0, stream>>>(batch, gstart, pooled);
    k_pool2<<<(NN + POOL_CHUNK - 1) / POOL_CHUNK, 256, 0, stream>>>(buf2, batch, pooled);
    k_head<<<1, 256, 0, stream>>>(pooled, gstart, Wf, bf, out);
}